// Round 1
// baseline (2969.736 us; speedup 1.0000x reference)
//
#include <hip/hip_runtime.h>

#define SLEN 2048
#define DIM  64
#define NH   8
#define TQ   16
#define NEG_INF -1e9f

// Block: 512 threads (8 waves), one (head, 16-q-row) tile per block.
// LDS: 16x2048 fp32 score tile (128 KB) + 16x64 Q tile (4 KB) = 132 KB -> 1 block/CU.
__global__ __launch_bounds__(512, 1)
void attn_fp32_kernel(const float* __restrict__ q,
                      const float* __restrict__ k,
                      const float* __restrict__ v,
                      const float* __restrict__ sph,
                      const int*   __restrict__ mask,
                      float* __restrict__ out,     // [H,S,D]
                      float* __restrict__ p_out)   // [H,S,S]
{
    __shared__ float  sS[TQ][SLEN];       // 128 KB score/prob tile
    __shared__ float4 sQ4[TQ][DIM / 4];   // 4 KB Q tile

    const int tid  = threadIdx.x;   // 0..511
    const int wave = tid >> 6;      // 0..7
    const int lane = tid & 63;
    const int bx   = blockIdx.x;    // 0..1023
    const int h    = bx >> 7;       // 8 heads
    const int qt   = bx & 127;      // 128 q-tiles
    const int qr0  = qt * TQ;

    // ---- load Q tile into LDS (16 rows x 16 float4) ----
    if (tid < TQ * (DIM / 4)) {
        int r  = tid >> 4;
        int d4 = tid & 15;
        sQ4[r][d4] = ((const float4*)(q + ((size_t)(h * SLEN + qr0 + r)) * DIM))[d4];
    }
    __syncthreads();

    // ---- phase 1: S = (Q/8) K^T * sph, masked -> LDS ----
    // Each thread handles 2 tasks; each task = one pair of k-columns for all 16 rows.
    for (int j = 0; j < 2; ++j) {
        const int task = tid + j * 512;     // 0..1023
        const int kk0  = task * 2;          // k-column pair
        const float4* K0 = (const float4*)(k + ((size_t)(h * SLEN + kk0)) * DIM);
        const float4* K1 = K0 + (DIM / 4);
        float acc0[TQ], acc1[TQ];
        #pragma unroll
        for (int r = 0; r < TQ; ++r) { acc0[r] = 0.f; acc1[r] = 0.f; }
        #pragma unroll
        for (int d4 = 0; d4 < DIM / 4; ++d4) {
            float4 k0 = K0[d4];
            float4 k1 = K1[d4];
            #pragma unroll
            for (int r = 0; r < TQ; ++r) {
                float4 q4 = sQ4[r][d4];   // wave-broadcast read
                acc0[r] += q4.x * k0.x + q4.y * k0.y + q4.z * k0.z + q4.w * k0.w;
                acc1[r] += q4.x * k1.x + q4.y * k1.y + q4.z * k1.z + q4.w * k1.w;
            }
        }
        #pragma unroll
        for (int r = 0; r < TQ; ++r) {
            size_t base = ((size_t)h * SLEN + (qr0 + r)) * SLEN + kk0;
            float2 sp = *((const float2*)(sph + base));   // coalesced b64
            int2   mk = *((const int2*)(mask + base));
            float s0 = (mk.x == 0) ? NEG_INF : acc0[r] * 0.125f * sp.x;
            float s1 = (mk.y == 0) ? NEG_INF : acc1[r] * 0.125f * sp.y;
            *((float2*)&sS[r][kk0]) = make_float2(s0, s1);
        }
    }
    __syncthreads();

    // ---- phase 2: row softmax (32 threads per row), write p_attn ----
    {
        const int row = tid >> 5;   // 0..15
        const int sub = tid & 31;
        float m = -3.4e38f;
        for (int i = 0; i < SLEN / 32; ++i)
            m = fmaxf(m, sS[row][sub + 32 * i]);
        #pragma unroll
        for (int off = 16; off >= 1; off >>= 1)
            m = fmaxf(m, __shfl_xor(m, off, 64));   // stays within 32-lane half
        float lsum = 0.f;
        for (int i = 0; i < SLEN / 32; ++i) {
            int idx = sub + 32 * i;
            float e = __expf(sS[row][idx] - m);
            sS[row][idx] = e;
            lsum += e;
        }
        #pragma unroll
        for (int off = 16; off >= 1; off >>= 1)
            lsum += __shfl_xor(lsum, off, 64);
        float inv = 1.0f / lsum;
        float* prow = p_out + ((size_t)(h * SLEN) + qr0 + row) * SLEN;
        for (int i = 0; i < SLEN / 32; ++i) {
            int idx = sub + 32 * i;
            float p = sS[row][idx] * inv;
            sS[row][idx] = p;
            prow[idx] = p;   // coalesced global write
        }
    }
    __syncthreads();

    // ---- phase 3: out = P @ V, split-K over 8 waves, lane = d ----
    {
        float acc[TQ];
        #pragma unroll
        for (int r = 0; r < TQ; ++r) acc[r] = 0.f;
        const int kbase = wave * (SLEN / 8);   // 256 k per wave
        for (int kc = 0; kc < (SLEN / 8) / 4; ++kc) {
            int kb = kbase + kc * 4;
            const float* vp = v + ((size_t)(h * SLEN + kb)) * DIM + lane;
            float v0 = vp[0 * DIM], v1 = vp[1 * DIM], v2 = vp[2 * DIM], v3 = vp[3 * DIM];
            #pragma unroll
            for (int r = 0; r < TQ; ++r) {
                float4 p4 = *((const float4*)&sS[r][kb]);  // wave-broadcast b128
                acc[r] += p4.x * v0 + p4.y * v1 + p4.z * v2 + p4.w * v3;
            }
        }
        __syncthreads();
        // reduce 8 wave-partials through (now free) score LDS
        float* part = &sS[0][0];    // [8][16][64] floats = 32 KB
        #pragma unroll
        for (int r = 0; r < TQ; ++r)
            part[(wave * TQ + r) * DIM + lane] = acc[r];
        __syncthreads();
        for (int o = tid; o < TQ * DIM; o += 512) {
            float s = 0.f;
            #pragma unroll
            for (int w = 0; w < 8; ++w) s += part[w * TQ * DIM + o];
            int r = o >> 6, d = o & 63;
            out[((size_t)(h * SLEN) + qr0 + r) * DIM + d] = s;
        }
    }
}

extern "C" void kernel_launch(void* const* d_in, const int* in_sizes, int n_in,
                              void* d_out, int out_size, void* d_ws, size_t ws_size,
                              hipStream_t stream) {
    const float* q    = (const float*)d_in[0];
    const float* k    = (const float*)d_in[1];
    const float* v    = (const float*)d_in[2];
    const float* sph  = (const float*)d_in[3];
    const int*   mask = (const int*)d_in[4];
    float* out   = (float*)d_out;                          // [8,2048,64]
    float* p_out = out + (size_t)NH * SLEN * DIM;          // [8,2048,2048]

    dim3 grid(NH * (SLEN / TQ));   // 1024 blocks
    dim3 block(512);
    hipLaunchKernelGGL(attn_fp32_kernel, grid, block, 0, stream,
                       q, k, v, sph, mask, out, p_out);
}

// Round 2
// 470.769 us; speedup vs baseline: 6.3083x; 6.3083x over previous
//
#include <hip/hip_runtime.h>

#define SLEN 2048
#define DIM  64
#define NH   8
#define TQ   16
#define NEG_INF -1e9f

typedef __attribute__((ext_vector_type(8))) short short8;
typedef __attribute__((ext_vector_type(4))) float f32x4;

__device__ inline unsigned short f2bf(float x) {
    unsigned u = __float_as_uint(x);
    u += 0x7fffu + ((u >> 16) & 1u);          // RNE (inputs finite)
    return (unsigned short)(u >> 16);
}
__device__ inline float bf2f(unsigned short b) {
    return __uint_as_float(((unsigned)b) << 16);
}

// ---- precompute: K -> bf16 hi/lo, V -> V^T bf16 ----
__global__ void conv_kernel(const float* __restrict__ k,
                            const float* __restrict__ v,
                            unsigned short* __restrict__ khi,
                            unsigned short* __restrict__ klo,
                            unsigned short* __restrict__ vt)
{
    int i = blockIdx.x * 256 + threadIdx.x;     // 0 .. 8*2048*64-1
    float x = k[i];
    unsigned short hi = f2bf(x);
    khi[i] = hi;
    klo[i] = f2bf(x - bf2f(hi));
    // vt output-indexed: i = (h*64 + d)*2048 + s  (coalesced write)
    int s  = i & (SLEN - 1);
    int hd = i >> 11;
    int d  = hd & (DIM - 1);
    int hh = hd >> 6;
    vt[i] = f2bf(v[((size_t)(hh * SLEN + s)) * DIM + d]);
}

// ---- main: one block = (head, 16 q-rows); 8 waves; MFMA everywhere ----
__global__ __launch_bounds__(512, 4)
void attn_mfma_kernel(const float* __restrict__ q,
                      const unsigned short* __restrict__ khi,
                      const unsigned short* __restrict__ klo,
                      const unsigned short* __restrict__ vt,
                      const float* __restrict__ sph,
                      const int*   __restrict__ mask,
                      float* __restrict__ out,     // [H,S,D]
                      float* __restrict__ p_out)   // [H,S,S]
{
    __shared__ unsigned short sP[TQ][SLEN + 8];   // p tile bf16, 65792 B
    __shared__ unsigned short sQhi[TQ][72];       // 2304 B
    __shared__ unsigned short sQlo[TQ][72];       // 2304 B
    __shared__ float sMax[TQ][8];                 // 512 B
    __shared__ float sSum[TQ][8];                 // 512 B
    __shared__ float sC[4][TQ][16];               // 4096 B   (total ~75.5 KB)

    const int tid  = threadIdx.x;
    const int wave = tid >> 6;
    const int lane = tid & 63;
    const int quad = lane >> 4;
    const int l16  = lane & 15;
    const int bx   = blockIdx.x;
    const int h    = bx >> 7;
    const int qr0  = (bx & 127) * TQ;

    // ---- Q tile load + hi/lo split into LDS ----
    {
        int e = tid * 2;
        int r = e >> 6, d = e & 63;
        float2 qv = *(const float2*)(q + ((size_t)(h * SLEN + qr0 + r)) * DIM + d);
        unsigned short h0 = f2bf(qv.x), h1 = f2bf(qv.y);
        sQhi[r][d]     = h0;
        sQhi[r][d + 1] = h1;
        sQlo[r][d]     = f2bf(qv.x - bf2f(h0));
        sQlo[r][d + 1] = f2bf(qv.y - bf2f(h1));
    }
    __syncthreads();

    // A-fragments for Q (persistent): A[m=l16][k=quad*8+j]
    short8 ah0 = *(const short8*)(&sQhi[l16][quad * 8]);
    short8 ah1 = *(const short8*)(&sQhi[l16][32 + quad * 8]);
    short8 al0 = *(const short8*)(&sQlo[l16][quad * 8]);
    short8 al1 = *(const short8*)(&sQlo[l16][32 + quad * 8]);

    const int n0 = wave * 256;   // this wave's 256 k-columns

    f32x4 c[16];
    #pragma unroll
    for (int t = 0; t < 16; ++t) c[t] = (f32x4){0.f, 0.f, 0.f, 0.f};

    // ---- QK^T: 16 n-tiles x (2 k-steps x 3 hi/lo terms) ----
    #pragma unroll
    for (int t = 0; t < 16; ++t) {
        const size_t rowb = ((size_t)(h * SLEN + n0 + t * 16 + l16)) * DIM + quad * 8;
        short8 bh0 = *(const short8*)(khi + rowb);
        short8 bh1 = *(const short8*)(khi + rowb + 32);
        short8 bl0 = *(const short8*)(klo + rowb);
        short8 bl1 = *(const short8*)(klo + rowb + 32);
        c[t] = __builtin_amdgcn_mfma_f32_16x16x32_bf16(ah0, bh0, c[t], 0, 0, 0);
        c[t] = __builtin_amdgcn_mfma_f32_16x16x32_bf16(ah1, bh1, c[t], 0, 0, 0);
        c[t] = __builtin_amdgcn_mfma_f32_16x16x32_bf16(ah0, bl0, c[t], 0, 0, 0);
        c[t] = __builtin_amdgcn_mfma_f32_16x16x32_bf16(ah1, bl1, c[t], 0, 0, 0);
        c[t] = __builtin_amdgcn_mfma_f32_16x16x32_bf16(al0, bh0, c[t], 0, 0, 0);
        c[t] = __builtin_amdgcn_mfma_f32_16x16x32_bf16(al1, bh1, c[t], 0, 0, 0);
    }

    // ---- sph * mask + per-row max (C layout: row = quad*4+j, col = n0+t*16+l16) ----
    float rmax[4] = {-3.4e38f, -3.4e38f, -3.4e38f, -3.4e38f};
    #pragma unroll
    for (int t = 0; t < 16; ++t) {
        #pragma unroll
        for (int j = 0; j < 4; ++j) {
            const size_t idx = ((size_t)(h * SLEN) + qr0 + quad * 4 + j) * SLEN + n0 + t * 16 + l16;
            float s = c[t][j] * 0.125f * sph[idx];
            s = (mask[idx] == 0) ? NEG_INF : s;
            c[t][j] = s;
            rmax[j] = fmaxf(rmax[j], s);
        }
    }
    #pragma unroll
    for (int off = 1; off <= 8; off <<= 1) {
        #pragma unroll
        for (int j = 0; j < 4; ++j)
            rmax[j] = fmaxf(rmax[j], __shfl_xor(rmax[j], off));
    }
    if (l16 == 0) {
        #pragma unroll
        for (int j = 0; j < 4; ++j) sMax[quad * 4 + j][wave] = rmax[j];
    }
    __syncthreads();

    float M[4];
    #pragma unroll
    for (int j = 0; j < 4; ++j) {
        float m = sMax[quad * 4 + j][0];
        #pragma unroll
        for (int w = 1; w < 8; ++w) m = fmaxf(m, sMax[quad * 4 + j][w]);
        M[j] = m;
    }

    float rsum[4] = {0.f, 0.f, 0.f, 0.f};
    #pragma unroll
    for (int t = 0; t < 16; ++t) {
        #pragma unroll
        for (int j = 0; j < 4; ++j) {
            float e = __expf(c[t][j] - M[j]);
            c[t][j] = e;
            rsum[j] += e;
        }
    }
    #pragma unroll
    for (int off = 1; off <= 8; off <<= 1) {
        #pragma unroll
        for (int j = 0; j < 4; ++j)
            rsum[j] += __shfl_xor(rsum[j], off);
    }
    if (l16 == 0) {
        #pragma unroll
        for (int j = 0; j < 4; ++j) sSum[quad * 4 + j][wave] = rsum[j];
    }
    __syncthreads();

    float inv[4];
    #pragma unroll
    for (int j = 0; j < 4; ++j) {
        float s = 0.f;
        #pragma unroll
        for (int w = 0; w < 8; ++w) s += sSum[quad * 4 + j][w];
        inv[j] = 1.0f / s;
    }

    // ---- normalize; write p fp32 to global, bf16 to LDS ----
    #pragma unroll
    for (int t = 0; t < 16; ++t) {
        #pragma unroll
        for (int j = 0; j < 4; ++j) {
            const int row = quad * 4 + j;
            const int col = n0 + t * 16 + l16;
            const size_t idx = ((size_t)(h * SLEN) + qr0 + row) * SLEN + col;
            float p = c[t][j] * inv[j];
            p_out[idx] = p;
            sP[row][col] = f2bf(p);
        }
    }
    __syncthreads();

    // ---- PV: wave -> (ntile = d-block, khalf); 32 k-steps of 32 ----
    const int ntile = wave & 3;
    const int khalf = wave >> 2;
    f32x4 o = (f32x4){0.f, 0.f, 0.f, 0.f};
    const unsigned short* vb = vt + ((size_t)(h * DIM + ntile * 16 + l16)) * SLEN
                                  + khalf * 1024 + quad * 8;
    #pragma unroll 8
    for (int s = 0; s < 32; ++s) {
        short8 a = *(const short8*)(&sP[l16][khalf * 1024 + s * 32 + quad * 8]);
        short8 b = *(const short8*)(vb + s * 32);
        o = __builtin_amdgcn_mfma_f32_16x16x32_bf16(a, b, o, 0, 0, 0);
    }
    if (wave >= 4) {
        #pragma unroll
        for (int j = 0; j < 4; ++j) sC[ntile][quad * 4 + j][l16] = o[j];
    }
    __syncthreads();
    if (wave < 4) {
        #pragma unroll
        for (int j = 0; j < 4; ++j) {
            float r = o[j] + sC[ntile][quad * 4 + j][l16];
            out[((size_t)(h * SLEN) + qr0 + quad * 4 + j) * DIM + ntile * 16 + l16] = r;
        }
    }
}

extern "C" void kernel_launch(void* const* d_in, const int* in_sizes, int n_in,
                              void* d_out, int out_size, void* d_ws, size_t ws_size,
                              hipStream_t stream) {
    const float* q    = (const float*)d_in[0];
    const float* k    = (const float*)d_in[1];
    const float* v    = (const float*)d_in[2];
    const float* sph  = (const float*)d_in[3];
    const int*   mask = (const int*)d_in[4];
    float* out   = (float*)d_out;                       // [8,2048,64]
    float* p_out = out + (size_t)NH * SLEN * DIM;       // [8,2048,2048]

    const size_t nkv = (size_t)NH * SLEN * DIM;         // 1,048,576
    unsigned short* khi = (unsigned short*)d_ws;        // 2 MB
    unsigned short* klo = khi + nkv;                    // 2 MB
    unsigned short* vt  = klo + nkv;                    // 2 MB

    hipLaunchKernelGGL(conv_kernel, dim3(nkv / 256), dim3(256), 0, stream,
                       k, v, khi, klo, vt);
    hipLaunchKernelGGL(attn_mfma_kernel, dim3(NH * (SLEN / TQ)), dim3(512), 0, stream,
                       q, khi, klo, vt, sph, mask, out, p_out);
}

// Round 3
// 417.560 us; speedup vs baseline: 7.1121x; 1.1274x over previous
//
#include <hip/hip_runtime.h>

#define SLEN 2048
#define DIM  64
#define NH   8
#define TQ   16
#define NEG_INF -1e9f

typedef __attribute__((ext_vector_type(8))) short short8;
typedef __attribute__((ext_vector_type(4))) float f32x4;
typedef unsigned short ushort;

__device__ inline ushort f2bf(float x) {
    unsigned u = __float_as_uint(x);
    u += 0x7fffu + ((u >> 16) & 1u);          // RNE (inputs finite)
    return (ushort)(u >> 16);
}
__device__ inline float bf2f(ushort b) {
    return __uint_as_float(((unsigned)b) << 16);
}

// ---- precompute 1: K -> bf16 hi/lo (vectorized, 4 elem/thread) ----
__global__ __launch_bounds__(256)
void convk_kernel(const float* __restrict__ k,
                  ushort* __restrict__ khi, ushort* __restrict__ klo)
{
    int i4 = blockIdx.x * 256 + threadIdx.x;      // float4 index
    float4 x = ((const float4*)k)[i4];
    ushort h0 = f2bf(x.x), h1 = f2bf(x.y), h2 = f2bf(x.z), h3 = f2bf(x.w);
    ushort4 hi = {h0, h1, h2, h3};
    ushort4 lo = {f2bf(x.x - bf2f(h0)), f2bf(x.y - bf2f(h1)),
                  f2bf(x.z - bf2f(h2)), f2bf(x.w - bf2f(h3))};
    ((ushort4*)khi)[i4] = hi;
    ((ushort4*)klo)[i4] = lo;
}

// ---- precompute 2: V -> V^T bf16 via LDS tile transpose ----
__global__ __launch_bounds__(256)
void convv_kernel(const float* __restrict__ v, ushort* __restrict__ vt)
{
    __shared__ ushort sT[64][70];     // [d][s], padded
    const int h  = blockIdx.x >> 5;
    const int st = blockIdx.x & 31;   // s-tile of 64
    const int t  = threadIdx.x;
    {
        const int r0 = t >> 4;            // s row (stride 16)
        const int c  = (t & 15) * 4;      // d col
        #pragma unroll
        for (int rr = r0; rr < 64; rr += 16) {
            float4 x = *(const float4*)(v + ((size_t)(h * SLEN + st * 64 + rr)) * DIM + c);
            sT[c + 0][rr] = f2bf(x.x);
            sT[c + 1][rr] = f2bf(x.y);
            sT[c + 2][rr] = f2bf(x.z);
            sT[c + 3][rr] = f2bf(x.w);
        }
    }
    __syncthreads();
    {
        const int d  = t >> 2;
        const int s0 = (t & 3) * 16;
        short8 a = *(const short8*)(&sT[d][s0]);
        short8 b = *(const short8*)(&sT[d][s0 + 8]);
        ushort* dst = vt + ((size_t)(h * DIM + d)) * SLEN + st * 64 + s0;
        *(short8*)(dst)     = a;
        *(short8*)(dst + 8) = b;
    }
}

// ---- main: one block = (head, 16 q-rows); 8 waves; MFMA everywhere ----
__global__ __launch_bounds__(512, 2)
void attn_mfma_kernel(const float* __restrict__ q,
                      const ushort* __restrict__ khi,
                      const ushort* __restrict__ klo,
                      const ushort* __restrict__ vt,
                      const float* __restrict__ sph,
                      const int*   __restrict__ mask,
                      float* __restrict__ out,     // [H,S,D]
                      float* __restrict__ p_out)   // [H,S,S]
{
    __shared__ ushort sP[TQ][SLEN + 8];   // p tile bf16, 65792 B
    __shared__ ushort sQhi[TQ][72];       // 2304 B
    __shared__ ushort sQlo[TQ][72];       // 2304 B
    __shared__ float sMax[TQ][8];         // 512 B
    __shared__ float sSum[TQ][8];         // 512 B
    __shared__ float sC[4][TQ][16];       // 4096 B   (total ~75.5 KB)

    const int tid  = threadIdx.x;
    const int wave = tid >> 6;
    const int lane = tid & 63;
    const int quad = lane >> 4;
    const int l16  = lane & 15;
    const int bx   = blockIdx.x;
    const int h    = bx >> 7;
    const int qr0  = (bx & 127) * TQ;

    // ---- Q tile load + hi/lo split into LDS ----
    {
        int e = tid * 2;
        int r = e >> 6, d = e & 63;
        float2 qv = *(const float2*)(q + ((size_t)(h * SLEN + qr0 + r)) * DIM + d);
        ushort h0 = f2bf(qv.x), h1 = f2bf(qv.y);
        sQhi[r][d]     = h0;
        sQhi[r][d + 1] = h1;
        sQlo[r][d]     = f2bf(qv.x - bf2f(h0));
        sQlo[r][d + 1] = f2bf(qv.y - bf2f(h1));
    }
    __syncthreads();

    // A-fragments for Q (persistent): A[m=l16][k=quad*8+j]
    short8 ah0 = *(const short8*)(&sQhi[l16][quad * 8]);
    short8 ah1 = *(const short8*)(&sQhi[l16][32 + quad * 8]);
    short8 al0 = *(const short8*)(&sQlo[l16][quad * 8]);
    short8 al1 = *(const short8*)(&sQlo[l16][32 + quad * 8]);

    const int n0 = wave * 256;   // this wave's 256 k-columns

    f32x4 c[16];
    #pragma unroll
    for (int t = 0; t < 16; ++t) c[t] = (f32x4){0.f, 0.f, 0.f, 0.f};

    // ---- QK^T: 16 n-tiles x (2 k-steps x 3 hi/lo terms) ----
    #pragma unroll
    for (int t = 0; t < 16; ++t) {
        const size_t rowb = ((size_t)(h * SLEN + n0 + t * 16 + l16)) * DIM + quad * 8;
        short8 bh0 = *(const short8*)(khi + rowb);
        short8 bh1 = *(const short8*)(khi + rowb + 32);
        short8 bl0 = *(const short8*)(klo + rowb);
        short8 bl1 = *(const short8*)(klo + rowb + 32);
        c[t] = __builtin_amdgcn_mfma_f32_16x16x32_bf16(ah0, bh0, c[t], 0, 0, 0);
        c[t] = __builtin_amdgcn_mfma_f32_16x16x32_bf16(ah1, bh1, c[t], 0, 0, 0);
        c[t] = __builtin_amdgcn_mfma_f32_16x16x32_bf16(ah0, bl0, c[t], 0, 0, 0);
        c[t] = __builtin_amdgcn_mfma_f32_16x16x32_bf16(ah1, bl1, c[t], 0, 0, 0);
        c[t] = __builtin_amdgcn_mfma_f32_16x16x32_bf16(al0, bh0, c[t], 0, 0, 0);
        c[t] = __builtin_amdgcn_mfma_f32_16x16x32_bf16(al1, bh1, c[t], 0, 0, 0);
    }

    // ---- sph * mask + per-row max; deep-MLP chunked loads ----
    // C layout: row = quad*4+j, col = n0 + t*16 + l16
    size_t rowb[4];
    #pragma unroll
    for (int j = 0; j < 4; ++j)
        rowb[j] = ((size_t)(h * SLEN) + qr0 + quad * 4 + j) * SLEN + n0 + l16;

    float rmax[4] = {-3.4e38f, -3.4e38f, -3.4e38f, -3.4e38f};
    #pragma unroll
    for (int half = 0; half < 2; ++half) {
        float sv[32];
        int   mv[32];
        #pragma unroll
        for (int u = 0; u < 32; ++u) {                 // issue 64 loads back-to-back
            const int t = half * 8 + (u >> 2), j = u & 3;
            sv[u] = __builtin_nontemporal_load(sph  + rowb[j] + t * 16);
            mv[u] = __builtin_nontemporal_load(mask + rowb[j] + t * 16);
        }
        #pragma unroll
        for (int u = 0; u < 32; ++u) {
            const int t = half * 8 + (u >> 2), j = u & 3;
            float s = c[t][j] * 0.125f * sv[u];
            s = (mv[u] == 0) ? NEG_INF : s;
            c[t][j] = s;
            rmax[j] = fmaxf(rmax[j], s);
        }
    }
    #pragma unroll
    for (int off = 1; off <= 8; off <<= 1) {
        #pragma unroll
        for (int j = 0; j < 4; ++j)
            rmax[j] = fmaxf(rmax[j], __shfl_xor(rmax[j], off));
    }
    if (l16 == 0) {
        #pragma unroll
        for (int j = 0; j < 4; ++j) sMax[quad * 4 + j][wave] = rmax[j];
    }
    __syncthreads();

    float M[4];
    #pragma unroll
    for (int j = 0; j < 4; ++j) {
        float m = sMax[quad * 4 + j][0];
        #pragma unroll
        for (int w = 1; w < 8; ++w) m = fmaxf(m, sMax[quad * 4 + j][w]);
        M[j] = m;
    }

    float rsum[4] = {0.f, 0.f, 0.f, 0.f};
    #pragma unroll
    for (int t = 0; t < 16; ++t) {
        #pragma unroll
        for (int j = 0; j < 4; ++j) {
            float e = __expf(c[t][j] - M[j]);
            c[t][j] = e;
            rsum[j] += e;
        }
    }
    #pragma unroll
    for (int off = 1; off <= 8; off <<= 1) {
        #pragma unroll
        for (int j = 0; j < 4; ++j)
            rsum[j] += __shfl_xor(rsum[j], off);
    }
    if (l16 == 0) {
        #pragma unroll
        for (int j = 0; j < 4; ++j) sSum[quad * 4 + j][wave] = rsum[j];
    }
    __syncthreads();

    float inv[4];
    #pragma unroll
    for (int j = 0; j < 4; ++j) {
        float s = 0.f;
        #pragma unroll
        for (int w = 0; w < 8; ++w) s += sSum[quad * 4 + j][w];
        inv[j] = 1.0f / s;
    }

    // ---- normalize; write p fp32 to global (nontemporal), bf16 to LDS ----
    #pragma unroll
    for (int t = 0; t < 16; ++t) {
        #pragma unroll
        for (int j = 0; j < 4; ++j) {
            const int row = quad * 4 + j;
            const int col = n0 + t * 16 + l16;
            float p = c[t][j] * inv[j];
            __builtin_nontemporal_store(p, p_out + rowb[j] + t * 16);
            sP[row][col] = f2bf(p);
        }
    }
    __syncthreads();

    // ---- PV: wave -> (ntile = d-block, khalf); 32 k-steps of 32 ----
    const int ntile = wave & 3;
    const int khalf = wave >> 2;
    f32x4 o = (f32x4){0.f, 0.f, 0.f, 0.f};
    const ushort* vb = vt + ((size_t)(h * DIM + ntile * 16 + l16)) * SLEN
                          + khalf * 1024 + quad * 8;
    #pragma unroll 8
    for (int s = 0; s < 32; ++s) {
        short8 a = *(const short8*)(&sP[l16][khalf * 1024 + s * 32 + quad * 8]);
        short8 b = *(const short8*)(vb + s * 32);
        o = __builtin_amdgcn_mfma_f32_16x16x32_bf16(a, b, o, 0, 0, 0);
    }
    if (wave >= 4) {
        #pragma unroll
        for (int j = 0; j < 4; ++j) sC[ntile][quad * 4 + j][l16] = o[j];
    }
    __syncthreads();
    if (wave < 4) {
        #pragma unroll
        for (int j = 0; j < 4; ++j) {
            float r = o[j] + sC[ntile][quad * 4 + j][l16];
            __builtin_nontemporal_store(
                r, out + ((size_t)(h * SLEN) + qr0 + quad * 4 + j) * DIM + ntile * 16 + l16);
        }
    }
}

extern "C" void kernel_launch(void* const* d_in, const int* in_sizes, int n_in,
                              void* d_out, int out_size, void* d_ws, size_t ws_size,
                              hipStream_t stream) {
    const float* q    = (const float*)d_in[0];
    const float* k    = (const float*)d_in[1];
    const float* v    = (const float*)d_in[2];
    const float* sph  = (const float*)d_in[3];
    const int*   mask = (const int*)d_in[4];
    float* out   = (float*)d_out;                       // [8,2048,64]
    float* p_out = out + (size_t)NH * SLEN * DIM;       // [8,2048,2048]

    const size_t nkv = (size_t)NH * SLEN * DIM;         // 1,048,576
    ushort* khi = (ushort*)d_ws;                        // 2 MB
    ushort* klo = khi + nkv;                            // 2 MB
    ushort* vt  = klo + nkv;                            // 2 MB

    hipLaunchKernelGGL(convk_kernel, dim3(nkv / 4 / 256), dim3(256), 0, stream,
                       k, khi, klo);
    hipLaunchKernelGGL(convv_kernel, dim3(NH * (SLEN / 64)), dim3(256), 0, stream,
                       v, vt);
    hipLaunchKernelGGL(attn_mfma_kernel, dim3(NH * (SLEN / TQ)), dim3(512), 0, stream,
                       q, khi, klo, vt, sph, mask, out, p_out);
}